// Round 11
// baseline (19.478 us; speedup 1.0000x reference)
//
#include <hip/hip_runtime.h>

// Problem constants: B=8, C=3, H=W=256, mask (B,1,H,W)
#define BB 8
#define CC 3
#define HH 256
#define WW 256
#define HWC (HH * WW)

// BIG = H+W = 512. With any border present every D^2 <= 2*255^2 < BIG^2, so
// (d2 >= BIG^2) <=> image has no border pixels (reference leaves D = 0 then).
#define BIGF 512.0f
#define BIG2F 262144.0f

#define LOG2G (-0.014499569695115089f)  // log2(0.99)
#define INV_N (1.0f / 1572864.0f)       // 1/(B*C*H*W)

// bv geometry: 256 threads = 8 cols x 32 segments x 8 rows; 256 blocks.
#define CT 8
#define SEGS 32
#define SR 8

#define NROW (BB * HH)  // 2048 row blocks

// ---------------------------------------------------------------------------
// Kernel 1: fused border (3x3 maxpool - mask) + vertical EDT -> g2.
__global__ __launch_bounds__(256) void bv_kernel(
    const float* __restrict__ mask, float* __restrict__ g2) {
  __shared__ float svmax[HH][CT + 3];   // vertical max3; halo cols 0 and CT+1
  __shared__ float dend[SEGS][CT];      // local down-scan value at segment end
  __shared__ float ufirst[SEGS][CT];    // first border index within segment

  int tid = threadIdx.x;
  int cl = tid & (CT - 1);
  int seg = tid >> 3;  // 0..31
  int tile = blockIdx.x & (WW / CT - 1);
  int b = blockIdx.x / (WW / CT);
  int c0 = tile * CT;
  int c = c0 + cl;
  int rs = seg * SR;
  const float* mb = mask + b * HWC;

  // Own-column mask rows rs-1..rs+SR (row-clamped; duplicates harmless under
  // max -- matches 'SAME' pooling).
  float mcol[SR + 2];
#pragma unroll
  for (int i = 0; i < SR + 2; ++i) {
    int r = rs - 1 + i;
    r = r < 0 ? 0 : (r > HH - 1 ? HH - 1 : r);
    mcol[i] = mb[r * WW + c];
  }
#pragma unroll
  for (int i = 0; i < SR; ++i)
    svmax[rs + i][cl + 1] = fmaxf(fmaxf(mcol[i], mcol[i + 1]), mcol[i + 2]);

  if (cl == 0 || cl == CT - 1) {  // halo columns, clamped
    int ch = (cl == 0) ? (c0 - 1 < 0 ? 0 : c0 - 1)
                       : (c0 + CT > WW - 1 ? WW - 1 : c0 + CT);
    int si = (cl == 0) ? 0 : CT + 1;
    int r0 = rs - 1 < 0 ? 0 : rs - 1;
    float h0 = mb[r0 * WW + ch];
    float h1 = mb[rs * WW + ch];
#pragma unroll
    for (int i = 0; i < SR; ++i) {
      int r2 = rs + 1 + i;
      r2 = r2 > HH - 1 ? HH - 1 : r2;
      float h2 = mb[r2 * WW + ch];
      svmax[rs + i][si] = fmaxf(fmaxf(h0, h1), h2);
      h0 = h1;
      h1 = h2;
    }
  }
  __syncthreads();

  // Border bits: 3x3 max - mask > 0.5.
  unsigned int bits = 0;
#pragma unroll
  for (int i = 0; i < SR; ++i) {
    float mx = fmaxf(fmaxf(svmax[rs + i][cl], svmax[rs + i][cl + 1]),
                     svmax[rs + i][cl + 2]);
    if ((mx - mcol[i + 1]) > 0.5f) bits |= (1u << i);
  }

  // Segment summaries.
  float carry = 4096.0f;
#pragma unroll
  for (int i = 0; i < SR; ++i) carry = (bits >> i & 1u) ? 0.0f : carry + 1.0f;
  dend[seg][cl] = carry;  // < SR iff segment contains a border
  ufirst[seg][cl] = bits ? (float)(__ffs(bits) - 1) : 4096.0f;
  __syncthreads();

  // Carry composition across segments (image-boundary init = BIG).
  float cinD = BIGF;
  for (int s = 0; s < seg; ++s) {
    float e = dend[s][cl];
    cinD = (e < (float)SR) ? e : cinD + (float)SR;
  }
  float cinU = BIGF;
  for (int s = SEGS - 1; s > seg; --s) {
    float f = ufirst[s][cl];
    cinU = (f < (float)SR) ? f : cinU + (float)SR;
  }

  // Final corrected scans from register bits; write g^2.
  float up[SR];
  float cu = 4096.0f;
#pragma unroll
  for (int i = SR - 1; i >= 0; --i) {
    cu = (bits >> i & 1u) ? 0.0f : cu + 1.0f;
    up[i] = cu;
  }
  float* gp = g2 + b * HWC + c;
  float cd = 4096.0f;
#pragma unroll
  for (int i = 0; i < SR; ++i) {
    cd = (bits >> i & 1u) ? 0.0f : cd + 1.0f;
    float d = fminf(cd, cinD + (float)(i + 1));
    float u = fminf(up[i], cinU + (float)(SR - i));
    float g = fminf(fminf(d, u), BIGF);
    gp[(rs + i) * WW] = g * g;
  }
}

// ---------------------------------------------------------------------------
// Kernel 2: min-plus over columns (exact EDT stage 2) + weight + L1; one
// plain partial store per block (no atomics/fences -- round-8 lesson). One
// block per (b,r) row; 2048 blocks for latency hiding (round-7 lesson).
// g2 row read directly from global (L1/L2-hot; bv just wrote it) -- no LDS
// staging, no mid-block barrier (round-9 lesson: keep the common path
// barrier-free). Dead waves skip the g2 reads entirely. 4-accumulator min
// chain (round-7 lesson: don't lengthen the dependent-min chain).
__global__ __launch_bounds__(256) void row_loss_kernel(
    const float* __restrict__ g2, const float* __restrict__ mask,
    const float* __restrict__ rec, const float* __restrict__ im,
    float* __restrict__ partials) {
  __shared__ float swave[4];
  int br = blockIdx.x;  // b*H + r
  int b = br >> 8;
  int r = br & 255;
  int c = threadIdx.x;
  int base = b * HWC + r * WW;

  float m = mask[base + c];

  float local = 0.0f;
  if (__ballot(m > 0.5f) != 0ULL) {  // per-wave skip (weight==0 if mask==0)
    const float* grow = g2 + base;
    float cf = (float)c;
    float a0 = 4.0f * BIG2F, a1 = a0, a2 = a0, a3 = a0;
#pragma unroll 8
    for (int cp = 0; cp < WW; cp += 4) {
      float4 s4 = *(const float4*)(grow + cp);
      float d0 = cf - (float)cp;
      float d1 = d0 - 1.0f;
      float dd = d0 - 2.0f;
      float d3 = d0 - 3.0f;
      a0 = fminf(a0, fmaf(d0, d0, s4.x));
      a1 = fminf(a1, fmaf(d1, d1, s4.y));
      a2 = fminf(a2, fmaf(dd, dd, s4.z));
      a3 = fminf(a3, fmaf(d3, d3, s4.w));
    }
    float d2 = fminf(fminf(a0, a1), fminf(a2, a3));
    float dist = (d2 >= BIG2F) ? 0.0f : sqrtf(d2);
    float wgt = exp2f(dist * m * LOG2G) * m;  // gamma^(dist*mask) * mask

    int pbase = b * CC * HWC + r * WW + c;
    float acc = 0.0f;
#pragma unroll
    for (int ch = 0; ch < CC; ++ch)
      acc += fabsf(rec[pbase + ch * HWC] - im[pbase + ch * HWC]);
    local = wgt * acc;
  }

  // Wave reduce, block reduce, plain partial store.
#pragma unroll
  for (int off = 32; off > 0; off >>= 1) local += __shfl_down(local, off, 64);
  if ((c & 63) == 0) swave[c >> 6] = local;
  __syncthreads();
  if (c == 0)
    partials[br] = swave[0] + swave[1] + swave[2] + swave[3];
}

// ---------------------------------------------------------------------------
// Kernel 3: finalize -- ONE wave sums the 2048 partials, writes the mean.
// Pure shuffle reduce: no LDS, no barrier.
__global__ __launch_bounds__(64) void finalize_kernel(
    const float* __restrict__ partials, float* __restrict__ out) {
  int t = threadIdx.x;  // 0..63
  float local = 0.0f;
#pragma unroll
  for (int i = 0; i < 8; ++i) {  // 8 independent float4 loads, overlap
    float4 p = *(const float4*)(partials + t * 4 + i * 256);
    local += (p.x + p.y) + (p.z + p.w);
  }
#pragma unroll
  for (int off = 32; off > 0; off >>= 1) local += __shfl_down(local, off, 64);
  if (t == 0) out[0] = local * INV_N;
}

// ---------------------------------------------------------------------------
extern "C" void kernel_launch(void* const* d_in, const int* in_sizes, int n_in,
                              void* d_out, int out_size, void* d_ws,
                              size_t ws_size, hipStream_t stream) {
  const float* rec = (const float*)d_in[0];
  const float* im = (const float*)d_in[1];
  const float* mask = (const float*)d_in[2];
  float* out = (float*)d_out;

  float* g2 = (float*)d_ws;                           // B*H*W floats = 2 MB
  float* partials = (float*)d_ws + (size_t)BB * HWC;  // NROW floats

  bv_kernel<<<BB * (WW / CT), 256, 0, stream>>>(mask, g2);
  row_loss_kernel<<<NROW, 256, 0, stream>>>(g2, mask, rec, im, partials);
  finalize_kernel<<<1, 64, 0, stream>>>(partials, out);
}

// Round 12
// 17.555 us; speedup vs baseline: 1.1095x; 1.1095x over previous
//
#include <hip/hip_runtime.h>

// Problem constants: B=8, C=3, H=W=256, mask (B,1,H,W)
#define BB 8
#define CC 3
#define HH 256
#define WW 256
#define HWC (HH * WW)

// BIG = H+W = 512. With any border present every D^2 <= 2*255^2 < BIG^2, so
// (d2 >= BIG^2) <=> image has no border pixels (reference leaves D = 0 then).
#define BIGF 512.0f
#define BIG2F 262144.0f

#define LOG2G (-0.014499569695115089f)  // log2(0.99)
#define INV_N (1.0f / 1572864.0f)       // 1/(B*C*H*W)

#define CT 16   // columns per tile
#define SEGS 16 // row segments per column
#define SR 16   // rows per segment

#define NROW (BB * HH)  // 2048 row blocks

// ---------------------------------------------------------------------------
// Kernel 1: fused border (3x3 maxpool - mask) + vertical EDT stage, writes
// g^2 = (min row-distance to border, capped at BIG)^2.
// Block = (b, 16-col tile): 256 threads = 16 cols x 16 segments x 16 rows.
__global__ __launch_bounds__(256) void bv_kernel(
    const float* __restrict__ mask, float* __restrict__ g2) {
  __shared__ float svmax[HH][CT + 3];   // vertical max3; halo cols 0 and CT+1
  __shared__ float dend[SEGS][CT];      // local down-scan value at segment end
  __shared__ float ufirst[SEGS][CT];    // first border index within segment

  int cl = threadIdx.x & (CT - 1);
  int seg = threadIdx.x / CT;
  int tile = blockIdx.x & (WW / CT - 1);  // 16 tiles per image
  int b = blockIdx.x / (WW / CT);
  int c0 = tile * CT;
  int c = c0 + cl;
  int rs = seg * SR;
  const float* mb = mask + b * HWC;

  // Own-column mask values for rows rs-1..rs+16 (row-clamped; duplicates at
  // image edges are harmless under max -- matches 'SAME' pooling).
  float mcol[SR + 2];
#pragma unroll
  for (int i = 0; i < SR + 2; ++i) {
    int r = rs - 1 + i;
    r = r < 0 ? 0 : (r > HH - 1 ? HH - 1 : r);
    mcol[i] = mb[r * WW + c];
  }
#pragma unroll
  for (int i = 0; i < SR; ++i)
    svmax[rs + i][cl + 1] = fmaxf(fmaxf(mcol[i], mcol[i + 1]), mcol[i + 2]);

  // Halo columns (c0-1, c0+16), column-clamped.
  if (cl == 0 || cl == CT - 1) {
    int ch = (cl == 0) ? (c0 - 1 < 0 ? 0 : c0 - 1)
                       : (c0 + CT > WW - 1 ? WW - 1 : c0 + CT);
    int si = (cl == 0) ? 0 : CT + 1;
    int r0 = rs - 1 < 0 ? 0 : rs - 1;
    float h0 = mb[r0 * WW + ch];
    float h1 = mb[rs * WW + ch];
#pragma unroll
    for (int i = 0; i < SR; ++i) {
      int r2 = rs + 1 + i;
      r2 = r2 > HH - 1 ? HH - 1 : r2;
      float h2 = mb[r2 * WW + ch];
      svmax[rs + i][si] = fmaxf(fmaxf(h0, h1), h2);
      h0 = h1;
      h1 = h2;
    }
  }
  __syncthreads();

  // Border bits for this (column, segment): 3x3 max - mask > 0.5.
  unsigned int bits = 0;
#pragma unroll
  for (int i = 0; i < SR; ++i) {
    float mx = fmaxf(fmaxf(svmax[rs + i][cl], svmax[rs + i][cl + 1]),
                     svmax[rs + i][cl + 2]);
    if ((mx - mcol[i + 1]) > 0.5f) bits |= (1u << i);
  }

  // Segment summaries.
  float carry = 4096.0f;
#pragma unroll
  for (int i = 0; i < SR; ++i) carry = (bits >> i & 1u) ? 0.0f : carry + 1.0f;
  dend[seg][cl] = carry;  // < SR iff segment contains a border
  ufirst[seg][cl] = bits ? (float)(__ffs(bits) - 1) : 4096.0f;
  __syncthreads();

  // Carry composition across segments (image-boundary init = BIG).
  float cinD = BIGF;
  for (int s = 0; s < seg; ++s) {
    float e = dend[s][cl];
    cinD = (e < (float)SR) ? e : cinD + (float)SR;
  }
  float cinU = BIGF;
  for (int s = SEGS - 1; s > seg; --s) {
    float f = ufirst[s][cl];
    cinU = (f < (float)SR) ? f : cinU + (float)SR;
  }

  // Final corrected scans from register bits; write g^2.
  float up[SR];
  float cu = 4096.0f;
#pragma unroll
  for (int i = SR - 1; i >= 0; --i) {
    cu = (bits >> i & 1u) ? 0.0f : cu + 1.0f;
    up[i] = cu;
  }
  float* gp = g2 + b * HWC + c;
  float cd = 4096.0f;
#pragma unroll
  for (int i = 0; i < SR; ++i) {
    cd = (bits >> i & 1u) ? 0.0f : cd + 1.0f;
    float d = fminf(cd, cinD + (float)(i + 1));
    float u = fminf(up[i], cinU + (float)(SR - i));
    float g = fminf(fminf(d, u), BIGF);
    gp[(rs + i) * WW] = g * g;
  }
}

// ---------------------------------------------------------------------------
// Kernel 2: min-plus over columns (exact EDT stage 2) + weight + L1; one
// plain partial store per block (no atomics/fences -- round-8 lesson). One
// block per (b,r) row; 2048 blocks for latency hiding (round-7 lesson).
// LDS-staged g2 row (broadcast ds_read beats redundant per-wave global
// reads -- round-11 lesson); 4-accumulator min chain (round-7 lesson).
__global__ __launch_bounds__(256) void row_loss_kernel(
    const float* __restrict__ g2, const float* __restrict__ mask,
    const float* __restrict__ rec, const float* __restrict__ im,
    float* __restrict__ partials) {
  __shared__ float srow[WW];
  __shared__ float swave[4];
  int br = blockIdx.x;  // b*H + r
  int b = br >> 8;
  int r = br & 255;
  int c = threadIdx.x;
  int base = b * HWC + r * WW;

  srow[c] = g2[base + c];
  float m = mask[base + c];
  __syncthreads();

  float local = 0.0f;
  if (__ballot(m > 0.5f) != 0ULL) {  // per-wave skip (weight==0 if mask==0)
    float cf = (float)c;
    float a0 = 4.0f * BIG2F, a1 = a0, a2 = a0, a3 = a0;
#pragma unroll 8
    for (int cp = 0; cp < WW; cp += 4) {
      float4 s4 = *(const float4*)(&srow[cp]);
      float d0 = cf - (float)cp;
      float d1 = d0 - 1.0f;
      float dd = d0 - 2.0f;
      float d3 = d0 - 3.0f;
      a0 = fminf(a0, fmaf(d0, d0, s4.x));
      a1 = fminf(a1, fmaf(d1, d1, s4.y));
      a2 = fminf(a2, fmaf(dd, dd, s4.z));
      a3 = fminf(a3, fmaf(d3, d3, s4.w));
    }
    float d2 = fminf(fminf(a0, a1), fminf(a2, a3));
    float dist = (d2 >= BIG2F) ? 0.0f : sqrtf(d2);
    float wgt = exp2f(dist * m * LOG2G) * m;  // gamma^(dist*mask) * mask

    int pbase = b * CC * HWC + r * WW + c;
    float acc = 0.0f;
#pragma unroll
    for (int ch = 0; ch < CC; ++ch)
      acc += fabsf(rec[pbase + ch * HWC] - im[pbase + ch * HWC]);
    local = wgt * acc;
  }

  // Wave reduce, block reduce, plain partial store.
#pragma unroll
  for (int off = 32; off > 0; off >>= 1) local += __shfl_down(local, off, 64);
  if ((c & 63) == 0) swave[c >> 6] = local;
  __syncthreads();
  if (c == 0)
    partials[br] = swave[0] + swave[1] + swave[2] + swave[3];
}

// ---------------------------------------------------------------------------
// Kernel 3: finalize -- one block sums the 2048 partials, writes the mean.
__global__ __launch_bounds__(256) void finalize_kernel(
    const float* __restrict__ partials, float* __restrict__ out) {
  __shared__ float swave[4];
  int t = threadIdx.x;
  float4 p0 = *(const float4*)(partials + t * 8);
  float4 p1 = *(const float4*)(partials + t * 8 + 4);
  float local = (p0.x + p0.y) + (p0.z + p0.w) + (p1.x + p1.y) + (p1.z + p1.w);
#pragma unroll
  for (int off = 32; off > 0; off >>= 1) local += __shfl_down(local, off, 64);
  if ((t & 63) == 0) swave[t >> 6] = local;
  __syncthreads();
  if (t == 0)
    out[0] = (swave[0] + swave[1] + swave[2] + swave[3]) * INV_N;
}

// ---------------------------------------------------------------------------
extern "C" void kernel_launch(void* const* d_in, const int* in_sizes, int n_in,
                              void* d_out, int out_size, void* d_ws,
                              size_t ws_size, hipStream_t stream) {
  const float* rec = (const float*)d_in[0];
  const float* im = (const float*)d_in[1];
  const float* mask = (const float*)d_in[2];
  float* out = (float*)d_out;

  float* g2 = (float*)d_ws;                           // B*H*W floats = 2 MB
  float* partials = (float*)d_ws + (size_t)BB * HWC;  // NROW floats

  bv_kernel<<<BB * (WW / CT), 256, 0, stream>>>(mask, g2);
  row_loss_kernel<<<NROW, 256, 0, stream>>>(g2, mask, rec, im, partials);
  finalize_kernel<<<1, 256, 0, stream>>>(partials, out);
}